// Round 5
// baseline (420.023 us; speedup 1.0000x reference)
//
#include <hip/hip_runtime.h>
#include <cstdint>
#include <cstddef>

#define NB 16
#define NC 84
#define NA 33600
#define NCLS 80
#define TOPK 1024
#define NBIN 8192        // coarse bins: mono_u32 >> 19 (sign+exp+4 mantissa bits)
#define CANDCAP 8192
#define SCORE_THR 0.005f
#define IOU_THR 0.5f
#define SBLK 33          // score blocks per batch: ceil((NA/4)/256)
#define RBLK 8           // rank blocks per batch

// ---- 64-bit sort key: (monotonic fp32) << 32 | ~index ----------------------
// Larger key == (higher score, then lower index) == jax.lax.top_k order.
__device__ __forceinline__ unsigned mono_u32(float f) {
    unsigned u = __float_as_uint(f);
    return (u & 0x80000000u) ? ~u : (u | 0x80000000u);
}
__device__ __forceinline__ float key_val(uint64_t k) {
    unsigned u = (unsigned)(k >> 32);
    u = (u & 0x80000000u) ? (u & 0x7FFFFFFFu) : ~u;
    return __uint_as_float(u);
}
__device__ __forceinline__ int key_idx(uint64_t k) {
    return (int)(~(uint32_t)(k & 0xFFFFFFFFu));
}

// ---- Phase 1: per-anchor max/argmax + LDS histogram + ticket-fused cut-bin -
// Blocks are batch-pure (SBLK per batch). Each block flushes its private
// histogram, fences, then takes a ticket; the last block per batch re-reads
// the global histogram via atomicAdd(.,0) (device-coherent point, safe across
// XCDs) and computes the cut bin (bin containing the 1024th-largest).
__global__ __launch_bounds__(256) void score_hist_kernel(const float* __restrict__ x,
                                                         float* __restrict__ sval,
                                                         int* __restrict__ cid,
                                                         unsigned* __restrict__ hist,
                                                         unsigned* __restrict__ done,
                                                         unsigned* __restrict__ cutbin) {
    int b = blockIdx.x / SBLK;
    int blk = blockIdx.x - b * SBLK;
    int t = threadIdx.x;
    __shared__ unsigned h[NBIN];
    __shared__ unsigned csum[256];
    __shared__ unsigned sticket;
    for (int i = t; i < NBIN; i += 256) h[i] = 0;
    __syncthreads();

    int q = blk * 256 + t;
    if (q < NA / 4) {
        const float4* p = (const float4*)(x + (size_t)b * NC * NA + (size_t)4 * NA) + q;
        float4 best = p[0];
        int4 bc = {0, 0, 0, 0};
#pragma unroll 8
        for (int c = 1; c < NCLS; ++c) {
            float4 v = p[(size_t)c * (NA / 4)];
            if (v.x > best.x) { best.x = v.x; bc.x = c; }
            if (v.y > best.y) { best.y = v.y; bc.y = c; }
            if (v.z > best.z) { best.z = v.z; bc.z = c; }
            if (v.w > best.w) { best.w = v.w; bc.w = c; }
        }
        float4 s;
        s.x = (best.x > SCORE_THR) ? best.x : -INFINITY;
        s.y = (best.y > SCORE_THR) ? best.y : -INFINITY;
        s.z = (best.z > SCORE_THR) ? best.z : -INFINITY;
        s.w = (best.w > SCORE_THR) ? best.w : -INFINITY;
        ((float4*)(sval + (size_t)b * NA))[q] = s;
        ((int4*)(cid + (size_t)b * NA))[q] = bc;
        atomicAdd(&h[mono_u32(s.x) >> 19], 1u);
        atomicAdd(&h[mono_u32(s.y) >> 19], 1u);
        atomicAdd(&h[mono_u32(s.z) >> 19], 1u);
        atomicAdd(&h[mono_u32(s.w) >> 19], 1u);
    }
    __syncthreads();
    unsigned* gh = hist + (size_t)b * NBIN;
    for (int i = t; i < NBIN; i += 256)
        if (h[i]) atomicAdd(&gh[i], h[i]);

    // release: each block's flush atomics are device-visible before its ticket
    __threadfence();
    __syncthreads();
    if (t == 0) sticket = atomicAdd(&done[b], 1u);
    __syncthreads();
    if (sticket == SBLK - 1) {
        // last block for batch b: suffix-scan histogram to find cut bin
        unsigned local = 0;
        for (int qq = 0; qq < 32; ++qq) {
            int bin = NBIN - 1 - (t * 32 + qq);
            unsigned v = atomicAdd(&gh[bin], 0u);   // device-coherent read
            h[bin] = v;                             // cache for the refine pass
            local += v;
        }
        csum[t] = local;
        __syncthreads();
        for (int off = 1; off < 256; off <<= 1) {
            unsigned v = (t >= off) ? csum[t - off] : 0u;
            __syncthreads();
            csum[t] += v;
            __syncthreads();
        }
        unsigned incl = csum[t], excl = incl - local;
        if (excl < TOPK && incl >= TOPK) {          // exactly one thread
            unsigned cum = excl;
            for (int qq = 0; qq < 32; ++qq) {
                int bin = NBIN - 1 - (t * 32 + qq);
                unsigned c = h[bin];
                if (cum + c >= TOPK) { cutbin[b] = (unsigned)bin; break; }
                cum += c;
            }
        }
    }
}

// ---- Phase 2b: wide compaction (proven round-2 version, verbatim) ----------
__global__ __launch_bounds__(256) void compact_kernel(const float* __restrict__ sval,
                                                      const unsigned* __restrict__ cutbin,
                                                      uint64_t* __restrict__ cand,
                                                      unsigned* __restrict__ cnt) {
    int gid = blockIdx.x * 256 + threadIdx.x;
    int b = gid / NA;
    int a = gid - b * NA;
    int b_first = (blockIdx.x * 256) / NA;   // block spans <=2 batches
    int seg = b - b_first;
    __shared__ unsigned lcnt[2], lbase[2];
    __shared__ uint64_t k0[256], k1[256];
    if (threadIdx.x < 2) lcnt[threadIdx.x] = 0;
    __syncthreads();
    unsigned u = mono_u32(sval[gid]);
    if ((u >> 19) >= cutbin[b]) {
        unsigned pos = atomicAdd(&lcnt[seg], 1u);
        uint64_t key = ((uint64_t)u << 32) | (uint32_t)(~(uint32_t)a);
        if (seg) k1[pos] = key; else k0[pos] = key;
    }
    __syncthreads();
    if (threadIdx.x == 0 && lcnt[0]) lbase[0] = atomicAdd(&cnt[b_first * 64], lcnt[0]);
    if (threadIdx.x == 1 && lcnt[1]) lbase[1] = atomicAdd(&cnt[(b_first + 1) * 64], lcnt[1]);
    __syncthreads();
    if (threadIdx.x < lcnt[0]) {
        unsigned p = lbase[0] + threadIdx.x;
        if (p < CANDCAP) cand[((size_t)b_first << 13) + p] = k0[threadIdx.x];
    }
    if (threadIdx.x < lcnt[1]) {
        unsigned p = lbase[1] + threadIdx.x;
        if (p < CANDCAP) cand[((size_t)(b_first + 1) << 13) + p] = k1[threadIdx.x];
    }
}

// ---- Phase 2c: rank-and-scatter from the FIXED global cand[] ordering ------
// (proven round-4 version, verbatim)
__global__ __launch_bounds__(256) void rank_kernel(const uint64_t* __restrict__ cand,
                                                   const unsigned* __restrict__ cnt,
                                                   const float* __restrict__ x,
                                                   const int* __restrict__ cid,
                                                   float* __restrict__ tval,
                                                   float* __restrict__ bx1, float* __restrict__ by1,
                                                   float* __restrict__ bx2, float* __restrict__ by2,
                                                   float* __restrict__ bar, int* __restrict__ tcid) {
    int b = blockIdx.x / RBLK;
    int sub = blockIdx.x - b * RBLK;
    int t = threadIdx.x;
    __shared__ uint64_t keys[CANDCAP];   // 64 KB
    unsigned C = cnt[b * 64];
    if (C > CANDCAP) C = CANDCAP;
    const uint64_t* cb = cand + ((size_t)b << 13);
    for (int i = t; i < (int)C; i += 256) keys[i] = cb[i];
    __syncthreads();

    const float* xb = x + (size_t)b * NC * NA;
    const int* cidb = cid + (size_t)b * NA;
    int base_o = b << 10;
    for (int p = sub * 256 + t; p < (int)C; p += RBLK * 256) {
        uint64_t ki = keys[p];
        unsigned rank = 0;
        int j = 0;
        // inner loop index is uniform across the wave -> LDS broadcast reads
        for (; j + 4 <= (int)C; j += 4) {
            rank += (keys[j]     > ki) ? 1u : 0u;
            rank += (keys[j + 1] > ki) ? 1u : 0u;
            rank += (keys[j + 2] > ki) ? 1u : 0u;
            rank += (keys[j + 3] > ki) ? 1u : 0u;
        }
        for (; j < (int)C; ++j) rank += (keys[j] > ki) ? 1u : 0u;
        if (rank < TOPK) {
            int o = base_o + (int)rank;
            tval[o] = key_val(ki);
            int idx = key_idx(ki);
            float X1 = xb[idx], Y1 = xb[NA + idx];
            float X2 = xb[2 * NA + idx], Y2 = xb[3 * NA + idx];
            bx1[o] = X1; by1[o] = Y1;
            bx2[o] = X2; by2[o] = Y2;
            bar[o] = (X2 - X1) * (Y2 - Y1);
            tcid[o] = cidb[idx];
        }
    }
}

// ---- Phase 3b: parallel suppression bit-matrix (64 rows/block) -------------
#define LDSPAD(j) ((j) + ((j) >> 6))
#define MBROWS 64
__global__ __launch_bounds__(256) void maskbuild_kernel(const float* __restrict__ bx1,
                                                        const float* __restrict__ by1,
                                                        const float* __restrict__ bx2,
                                                        const float* __restrict__ by2,
                                                        const float* __restrict__ bar,
                                                        const float* __restrict__ tval,
                                                        uint64_t* __restrict__ M,
                                                        int* __restrict__ rowflag) {
    int b = blockIdx.x >> 4;
    int r0 = (blockIdx.x & 15) << 6;
    int t = threadIdx.x;
    int rsub = t & 15;
    int w = t >> 4;
    int base = b << 10;
    __shared__ float sx1[TOPK + 16], sy1[TOPK + 16], sx2[TOPK + 16], sy2[TOPK + 16], sar[TOPK + 16];
    __shared__ unsigned aflag[MBROWS];

    for (int j = t; j < TOPK; j += 256) {
        int ji = LDSPAD(j);
        sx1[ji] = bx1[base + j]; sy1[ji] = by1[base + j];
        sx2[ji] = bx2[base + j]; sy2[ji] = by2[base + j];
        sar[ji] = bar[base + j];
    }
    if (t < MBROWS) aflag[t] = 0;
    __syncthreads();

#pragma unroll
    for (int rr = 0; rr < 4; ++rr) {
        int r = r0 + (rr << 4) + rsub;
        int ri = LDSPAD(r);
        float ix1 = sx1[ri], iy1 = sy1[ri], ix2 = sx2[ri], iy2 = sy2[ri], ia = sar[ri];
        uint64_t m = 0;
        if (((w << 6) + 63) > r) {        // chunk has at least one j > r
#pragma unroll 8
            for (int jj = 0; jj < 64; ++jj) {
                int j = (w << 6) + jj;
                int ji = w * 65 + jj;
                float ltx = fmaxf(ix1, sx1[ji]);
                float lty = fmaxf(iy1, sy1[ji]);
                float rbx = fminf(ix2, sx2[ji]);
                float rby = fminf(iy2, sy2[ji]);
                float ww = fmaxf(rbx - ltx, 0.0f);
                float hh = fmaxf(rby - lty, 0.0f);
                float inter = ww * hh;
                float uni = ia + sar[ji] - inter;      // same op order as reference
                float iou = inter / fmaxf(uni, 1e-9f);
                if (j > r && iou > IOU_THR) m |= (1ULL << jj);
            }
        }
        M[((size_t)(base + r) << 4) + w] = m;
        if (m) atomicOr(&aflag[(rr << 4) + rsub], 1u);
    }
    __syncthreads();
    if (t < MBROWS) {
        int r = r0 + t;
        bool valid = tval[base + r] > SCORE_THR;
        rowflag[base + r] = (aflag[t] && valid) ? 1 : 0;
    }
}

// ---- Phase 3c: serial greedy sweep, register-staged rows + epilogue --------
__global__ __launch_bounds__(64) void sweep_kernel(const uint64_t* __restrict__ M,
                                                   const int* __restrict__ rowflag,
                                                   const float* __restrict__ tval,
                                                   const int* __restrict__ tcid,
                                                   const float* __restrict__ bx1,
                                                   const float* __restrict__ by1,
                                                   const float* __restrict__ bx2,
                                                   const float* __restrict__ by2,
                                                   float* __restrict__ out) {
    int b = blockIdx.x;
    int l = threadIdx.x;
    int base = b << 10;
    int w = l & 15, g = l >> 4;
    __shared__ int list[TOPK];

    float tv[16];
#pragma unroll
    for (int s = 0; s < 16; ++s) tv[s] = tval[base + (s << 6) + l];

    uint64_t vword = 0;
#pragma unroll
    for (int s = 0; s < 16; ++s) {
        uint64_t bal = __ballot(tv[s] > SCORE_THR);
        if (l == s) vword = bal;
    }

    int cnt = 0;
#pragma unroll
    for (int s = 0; s < 16; ++s) {
        int flag = rowflag[base + (s << 6) + l];
        uint64_t m = __ballot(flag != 0);
        if (flag) {
            int pos = cnt + __popcll(m & ((1ULL << l) - 1ULL));
            list[pos] = (s << 6) + l;
        }
        cnt += __popcll(m);
    }
    __syncthreads();

    uint64_t remv = 0;
    for (int chunk = 0; chunk < cnt; chunk += 64) {
        int m = min(64, cnt - chunk);
        int idx_l = chunk + l;
        int myi = list[(idx_l < cnt) ? idx_l : 0];
        uint64_t rows[16];
#pragma unroll
        for (int q = 0; q < 16; ++q) {
            int it = chunk + q * 4 + g;
            int it2 = (it < cnt) ? it : 0;
            uint64_t v = M[((size_t)(base + list[it2]) << 4) + w];
            rows[q] = (it < cnt) ? v : 0ULL;
        }
        for (int r = 0; r < m; ++r) {
            int i = __shfl(myi, r, 64);
            uint64_t row = __shfl(rows[r >> 2], ((r & 3) << 4) + w, 64);
            uint64_t rb = __shfl(remv, i >> 6, 64);
            bool kept = !((rb >> (i & 63)) & 1ULL);
            remv |= (kept && l < 16) ? row : 0ULL;
        }
    }

    uint64_t kf = vword & ~remv;
#pragma unroll
    for (int s = 0; s < 16; ++s) {
        uint64_t kw = __shfl(kf, s, 64);
        bool kp = (kw >> l) & 1ULL;
        int k = (s << 6) + l;
        float x1 = bx1[base + k], y1 = by1[base + k];
        float x2 = bx2[base + k], y2 = by2[base + k];
        float* po = out + ((size_t)(base + k)) * 6;
        po[0] = kp ? x1 : 0.0f;
        po[1] = kp ? y1 : 0.0f;
        po[2] = kp ? x2 : 0.0f;
        po[3] = kp ? y2 : 0.0f;
        po[4] = kp ? tv[s] : 0.0f;
        po[5] = kp ? (float)tcid[base + k] : 0.0f;
        out[(size_t)NB * TOPK * 6 + base + k] = kp ? 1.0f : 0.0f;
    }
}

extern "C" void kernel_launch(void* const* d_in, const int* in_sizes, int n_in,
                              void* d_out, int out_size, void* d_ws, size_t ws_size,
                              hipStream_t stream) {
    const float* x = (const float*)d_in[0];
    float* out = (float*)d_out;
    char* ws = (char*)d_ws;

    size_t off = 0;
    auto alloc = [&](size_t bytes) { void* p = ws + off; off = (off + bytes + 255) & ~(size_t)255; return p; };
    float*    sval    = (float*)alloc((size_t)NB * NA * 4);
    int*      cid     = (int*)alloc((size_t)NB * NA * 4);
    unsigned* hist    = (unsigned*)alloc((size_t)NB * NBIN * 4);   // 512 KB
    unsigned* cnt     = (unsigned*)alloc((size_t)NB * 64 * 4);     // 4 KB, contiguous
    unsigned* done    = (unsigned*)alloc((size_t)NB * 4);          // 256 B slot, contiguous
    unsigned* cutbin  = (unsigned*)alloc(NB * 4);
    uint64_t* cand    = (uint64_t*)alloc((size_t)NB * CANDCAP * 8);
    float*    tval    = (float*)alloc((size_t)NB * TOPK * 4);
    float*    bx1     = (float*)alloc((size_t)NB * TOPK * 4);
    float*    by1     = (float*)alloc((size_t)NB * TOPK * 4);
    float*    bx2     = (float*)alloc((size_t)NB * TOPK * 4);
    float*    by2     = (float*)alloc((size_t)NB * TOPK * 4);
    float*    bar     = (float*)alloc((size_t)NB * TOPK * 4);
    int*      tcid    = (int*)alloc((size_t)NB * TOPK * 4);
    int*      rowflag = (int*)alloc((size_t)NB * TOPK * 4);
    uint64_t* M       = (uint64_t*)alloc((size_t)NB * TOPK * 16 * 8);

    // single memset: hist (512 KB) + cnt (4 KB) + done (256 B), contiguous
    hipMemsetAsync(hist, 0, (size_t)NB * NBIN * 4 + (size_t)NB * 64 * 4 + 256, stream);

    score_hist_kernel<<<NB * SBLK, 256, 0, stream>>>(x, sval, cid, hist, done, cutbin);
    compact_kernel<<<NB * NA / 256, 256, 0, stream>>>(sval, cutbin, cand, cnt);
    rank_kernel<<<NB * RBLK, 256, 0, stream>>>(cand, cnt, x, cid, tval, bx1, by1, bx2, by2, bar, tcid);
    maskbuild_kernel<<<NB * 16, 256, 0, stream>>>(bx1, by1, bx2, by2, bar, tval, M, rowflag);
    sweep_kernel<<<NB, 64, 0, stream>>>(M, rowflag, tval, tcid, bx1, by1, bx2, by2, out);
}

// Round 6
// 349.845 us; speedup vs baseline: 1.2006x; 1.2006x over previous
//
#include <hip/hip_runtime.h>
#include <cstdint>
#include <cstddef>

#define NB 16
#define NC 84
#define NA 33600
#define NCLS 80
#define TOPK 1024
#define NBIN 8192        // coarse bins: mono_u32 >> 19 (sign+exp+4 mantissa bits)
#define CANDCAP 8192
#define SCORE_THR 0.005f
#define IOU_THR 0.5f
#define SBLK 33          // score blocks per batch: ceil((NA/4)/256)
#define RBLK 8           // rank blocks per batch

// ---- 64-bit sort key: (monotonic fp32) << 32 | ~index ----------------------
// Larger key == (higher score, then lower index) == jax.lax.top_k order.
__device__ __forceinline__ unsigned mono_u32(float f) {
    unsigned u = __float_as_uint(f);
    return (u & 0x80000000u) ? ~u : (u | 0x80000000u);
}
__device__ __forceinline__ float key_val(uint64_t k) {
    unsigned u = (unsigned)(k >> 32);
    u = (u & 0x80000000u) ? (u & 0x7FFFFFFFu) : ~u;
    return __uint_as_float(u);
}
__device__ __forceinline__ int key_idx(uint64_t k) {
    return (int)(~(uint32_t)(k & 0xFFFFFFFFu));
}

// ---- Phase 1: per-anchor max/argmax over 80 classes + fused LDS histogram --
// (proven round-2/round-4 version, verbatim; unroll 4, no fence/ticket)
__global__ __launch_bounds__(256) void score_hist_kernel(const float* __restrict__ x,
                                                         float* __restrict__ sval,
                                                         int* __restrict__ cid,
                                                         unsigned* __restrict__ hist) {
    int b = blockIdx.x / SBLK;
    int blk = blockIdx.x - b * SBLK;
    int t = threadIdx.x;
    __shared__ unsigned h[NBIN];
    for (int i = t; i < NBIN; i += 256) h[i] = 0;
    __syncthreads();

    int q = blk * 256 + t;
    if (q < NA / 4) {
        const float4* p = (const float4*)(x + (size_t)b * NC * NA + (size_t)4 * NA) + q;
        float4 best = p[0];
        int4 bc = {0, 0, 0, 0};
#pragma unroll 4
        for (int c = 1; c < NCLS; ++c) {
            float4 v = p[(size_t)c * (NA / 4)];
            if (v.x > best.x) { best.x = v.x; bc.x = c; }
            if (v.y > best.y) { best.y = v.y; bc.y = c; }
            if (v.z > best.z) { best.z = v.z; bc.z = c; }
            if (v.w > best.w) { best.w = v.w; bc.w = c; }
        }
        float4 s;
        s.x = (best.x > SCORE_THR) ? best.x : -INFINITY;
        s.y = (best.y > SCORE_THR) ? best.y : -INFINITY;
        s.z = (best.z > SCORE_THR) ? best.z : -INFINITY;
        s.w = (best.w > SCORE_THR) ? best.w : -INFINITY;
        ((float4*)(sval + (size_t)b * NA))[q] = s;
        ((int4*)(cid + (size_t)b * NA))[q] = bc;
        atomicAdd(&h[mono_u32(s.x) >> 19], 1u);
        atomicAdd(&h[mono_u32(s.y) >> 19], 1u);
        atomicAdd(&h[mono_u32(s.z) >> 19], 1u);
        atomicAdd(&h[mono_u32(s.w) >> 19], 1u);
    }
    __syncthreads();
    unsigned* gh = hist + (size_t)b * NBIN;
    for (int i = t; i < NBIN; i += 256)
        if (h[i]) atomicAdd(&gh[i], h[i]);
}

// ---- Phase 2a: per-batch cut bin (proven round-2 version, verbatim) --------
__global__ __launch_bounds__(256) void scan_kernel(const unsigned* __restrict__ hist,
                                                   unsigned* __restrict__ cutbin) {
    int b = blockIdx.x;
    int t = threadIdx.x;
    __shared__ unsigned csum[256];
    const unsigned* h = hist + (size_t)b * NBIN;
    unsigned local = 0;
#pragma unroll 8
    for (int q = 0; q < 32; ++q) local += h[NBIN - 1 - (t * 32 + q)];
    csum[t] = local;
    __syncthreads();
    for (int off = 1; off < 256; off <<= 1) {
        unsigned v = (t >= off) ? csum[t - off] : 0u;
        __syncthreads();
        csum[t] += v;
        __syncthreads();
    }
    unsigned incl = csum[t], excl = incl - local;
    if (excl < TOPK && incl >= TOPK) {          // exactly one thread
        unsigned cum = excl;
        for (int q = 0; q < 32; ++q) {
            unsigned bin = NBIN - 1 - (t * 32 + q);
            unsigned c = h[bin];
            if (cum + c >= TOPK) { cutbin[b] = bin; break; }
            cum += c;
        }
    }
}

// ---- Phase 2b: wide compaction (proven round-2 version, verbatim) ----------
__global__ __launch_bounds__(256) void compact_kernel(const float* __restrict__ sval,
                                                      const unsigned* __restrict__ cutbin,
                                                      uint64_t* __restrict__ cand,
                                                      unsigned* __restrict__ cnt) {
    int gid = blockIdx.x * 256 + threadIdx.x;
    int b = gid / NA;
    int a = gid - b * NA;
    int b_first = (blockIdx.x * 256) / NA;   // block spans <=2 batches
    int seg = b - b_first;
    __shared__ unsigned lcnt[2], lbase[2];
    __shared__ uint64_t k0[256], k1[256];
    if (threadIdx.x < 2) lcnt[threadIdx.x] = 0;
    __syncthreads();
    unsigned u = mono_u32(sval[gid]);
    if ((u >> 19) >= cutbin[b]) {
        unsigned pos = atomicAdd(&lcnt[seg], 1u);
        uint64_t key = ((uint64_t)u << 32) | (uint32_t)(~(uint32_t)a);
        if (seg) k1[pos] = key; else k0[pos] = key;
    }
    __syncthreads();
    if (threadIdx.x == 0 && lcnt[0]) lbase[0] = atomicAdd(&cnt[b_first * 64], lcnt[0]);
    if (threadIdx.x == 1 && lcnt[1]) lbase[1] = atomicAdd(&cnt[(b_first + 1) * 64], lcnt[1]);
    __syncthreads();
    if (threadIdx.x < lcnt[0]) {
        unsigned p = lbase[0] + threadIdx.x;
        if (p < CANDCAP) cand[((size_t)b_first << 13) + p] = k0[threadIdx.x];
    }
    if (threadIdx.x < lcnt[1]) {
        unsigned p = lbase[1] + threadIdx.x;
        if (p < CANDCAP) cand[((size_t)(b_first + 1) << 13) + p] = k1[threadIdx.x];
    }
}

// ---- Phase 2c: rank-and-scatter from the FIXED global cand[] ordering ------
// All RBLK blocks of a batch read the same global array, so position-based
// partitioning covers every key exactly once. Keys are unique (index
// tie-break) -> ranks are distinct; C >= TOPK by cut-bin construction, so
// ranks 0..1023 are each written exactly once, in exact jax.lax.top_k order.
// Box/area/class gather fused into the scatter (replaces sortk + boxes).
__global__ __launch_bounds__(256) void rank_kernel(const uint64_t* __restrict__ cand,
                                                   const unsigned* __restrict__ cnt,
                                                   const float* __restrict__ x,
                                                   const int* __restrict__ cid,
                                                   float* __restrict__ tval,
                                                   float* __restrict__ bx1, float* __restrict__ by1,
                                                   float* __restrict__ bx2, float* __restrict__ by2,
                                                   float* __restrict__ bar, int* __restrict__ tcid) {
    int b = blockIdx.x / RBLK;
    int sub = blockIdx.x - b * RBLK;
    int t = threadIdx.x;
    __shared__ uint64_t keys[CANDCAP];   // 64 KB
    unsigned C = cnt[b * 64];
    if (C > CANDCAP) C = CANDCAP;
    const uint64_t* cb = cand + ((size_t)b << 13);
    for (int i = t; i < (int)C; i += 256) keys[i] = cb[i];
    __syncthreads();

    const float* xb = x + (size_t)b * NC * NA;
    const int* cidb = cid + (size_t)b * NA;
    int base_o = b << 10;
    for (int p = sub * 256 + t; p < (int)C; p += RBLK * 256) {
        uint64_t ki = keys[p];
        unsigned rank = 0;
        int j = 0;
        // inner loop index is uniform across the wave -> LDS broadcast reads
        for (; j + 4 <= (int)C; j += 4) {
            rank += (keys[j]     > ki) ? 1u : 0u;
            rank += (keys[j + 1] > ki) ? 1u : 0u;
            rank += (keys[j + 2] > ki) ? 1u : 0u;
            rank += (keys[j + 3] > ki) ? 1u : 0u;
        }
        for (; j < (int)C; ++j) rank += (keys[j] > ki) ? 1u : 0u;
        if (rank < TOPK) {
            int o = base_o + (int)rank;
            tval[o] = key_val(ki);
            int idx = key_idx(ki);
            float X1 = xb[idx], Y1 = xb[NA + idx];
            float X2 = xb[2 * NA + idx], Y2 = xb[3 * NA + idx];
            bx1[o] = X1; by1[o] = Y1;
            bx2[o] = X2; by2[o] = Y2;
            bar[o] = (X2 - X1) * (Y2 - Y1);
            tcid[o] = cidb[idx];
        }
    }
}

// ---- Phase 3b: parallel suppression bit-matrix (64 rows/block) -------------
#define LDSPAD(j) ((j) + ((j) >> 6))
#define MBROWS 64
__global__ __launch_bounds__(256) void maskbuild_kernel(const float* __restrict__ bx1,
                                                        const float* __restrict__ by1,
                                                        const float* __restrict__ bx2,
                                                        const float* __restrict__ by2,
                                                        const float* __restrict__ bar,
                                                        const float* __restrict__ tval,
                                                        uint64_t* __restrict__ M,
                                                        int* __restrict__ rowflag) {
    int b = blockIdx.x >> 4;
    int r0 = (blockIdx.x & 15) << 6;
    int t = threadIdx.x;
    int rsub = t & 15;
    int w = t >> 4;
    int base = b << 10;
    __shared__ float sx1[TOPK + 16], sy1[TOPK + 16], sx2[TOPK + 16], sy2[TOPK + 16], sar[TOPK + 16];
    __shared__ unsigned aflag[MBROWS];

    for (int j = t; j < TOPK; j += 256) {
        int ji = LDSPAD(j);
        sx1[ji] = bx1[base + j]; sy1[ji] = by1[base + j];
        sx2[ji] = bx2[base + j]; sy2[ji] = by2[base + j];
        sar[ji] = bar[base + j];
    }
    if (t < MBROWS) aflag[t] = 0;
    __syncthreads();

#pragma unroll
    for (int rr = 0; rr < 4; ++rr) {
        int r = r0 + (rr << 4) + rsub;
        int ri = LDSPAD(r);
        float ix1 = sx1[ri], iy1 = sy1[ri], ix2 = sx2[ri], iy2 = sy2[ri], ia = sar[ri];
        uint64_t m = 0;
        if (((w << 6) + 63) > r) {        // chunk has at least one j > r
#pragma unroll 8
            for (int jj = 0; jj < 64; ++jj) {
                int j = (w << 6) + jj;
                int ji = w * 65 + jj;
                float ltx = fmaxf(ix1, sx1[ji]);
                float lty = fmaxf(iy1, sy1[ji]);
                float rbx = fminf(ix2, sx2[ji]);
                float rby = fminf(iy2, sy2[ji]);
                float ww = fmaxf(rbx - ltx, 0.0f);
                float hh = fmaxf(rby - lty, 0.0f);
                float inter = ww * hh;
                float uni = ia + sar[ji] - inter;      // same op order as reference
                float iou = inter / fmaxf(uni, 1e-9f);
                if (j > r && iou > IOU_THR) m |= (1ULL << jj);
            }
        }
        M[((size_t)(base + r) << 4) + w] = m;
        if (m) atomicOr(&aflag[(rr << 4) + rsub], 1u);
    }
    __syncthreads();
    if (t < MBROWS) {
        int r = r0 + t;
        bool valid = tval[base + r] > SCORE_THR;
        rowflag[base + r] = (aflag[t] && valid) ? 1 : 0;
    }
}

// ---- Phase 3c: serial greedy sweep, register-staged rows + epilogue --------
__global__ __launch_bounds__(64) void sweep_kernel(const uint64_t* __restrict__ M,
                                                   const int* __restrict__ rowflag,
                                                   const float* __restrict__ tval,
                                                   const int* __restrict__ tcid,
                                                   const float* __restrict__ bx1,
                                                   const float* __restrict__ by1,
                                                   const float* __restrict__ bx2,
                                                   const float* __restrict__ by2,
                                                   float* __restrict__ out) {
    int b = blockIdx.x;
    int l = threadIdx.x;
    int base = b << 10;
    int w = l & 15, g = l >> 4;
    __shared__ int list[TOPK];

    float tv[16];
#pragma unroll
    for (int s = 0; s < 16; ++s) tv[s] = tval[base + (s << 6) + l];

    uint64_t vword = 0;
#pragma unroll
    for (int s = 0; s < 16; ++s) {
        uint64_t bal = __ballot(tv[s] > SCORE_THR);
        if (l == s) vword = bal;
    }

    int cnt = 0;
#pragma unroll
    for (int s = 0; s < 16; ++s) {
        int flag = rowflag[base + (s << 6) + l];
        uint64_t m = __ballot(flag != 0);
        if (flag) {
            int pos = cnt + __popcll(m & ((1ULL << l) - 1ULL));
            list[pos] = (s << 6) + l;
        }
        cnt += __popcll(m);
    }
    __syncthreads();

    uint64_t remv = 0;
    for (int chunk = 0; chunk < cnt; chunk += 64) {
        int m = min(64, cnt - chunk);
        int idx_l = chunk + l;
        int myi = list[(idx_l < cnt) ? idx_l : 0];
        uint64_t rows[16];
#pragma unroll
        for (int q = 0; q < 16; ++q) {
            int it = chunk + q * 4 + g;
            int it2 = (it < cnt) ? it : 0;
            uint64_t v = M[((size_t)(base + list[it2]) << 4) + w];
            rows[q] = (it < cnt) ? v : 0ULL;
        }
        for (int r = 0; r < m; ++r) {
            int i = __shfl(myi, r, 64);
            uint64_t row = __shfl(rows[r >> 2], ((r & 3) << 4) + w, 64);
            uint64_t rb = __shfl(remv, i >> 6, 64);
            bool kept = !((rb >> (i & 63)) & 1ULL);
            remv |= (kept && l < 16) ? row : 0ULL;
        }
    }

    uint64_t kf = vword & ~remv;
#pragma unroll
    for (int s = 0; s < 16; ++s) {
        uint64_t kw = __shfl(kf, s, 64);
        bool kp = (kw >> l) & 1ULL;
        int k = (s << 6) + l;
        float x1 = bx1[base + k], y1 = by1[base + k];
        float x2 = bx2[base + k], y2 = by2[base + k];
        float* po = out + ((size_t)(base + k)) * 6;
        po[0] = kp ? x1 : 0.0f;
        po[1] = kp ? y1 : 0.0f;
        po[2] = kp ? x2 : 0.0f;
        po[3] = kp ? y2 : 0.0f;
        po[4] = kp ? tv[s] : 0.0f;
        po[5] = kp ? (float)tcid[base + k] : 0.0f;
        out[(size_t)NB * TOPK * 6 + base + k] = kp ? 1.0f : 0.0f;
    }
}

extern "C" void kernel_launch(void* const* d_in, const int* in_sizes, int n_in,
                              void* d_out, int out_size, void* d_ws, size_t ws_size,
                              hipStream_t stream) {
    const float* x = (const float*)d_in[0];
    float* out = (float*)d_out;
    char* ws = (char*)d_ws;

    size_t off = 0;
    auto alloc = [&](size_t bytes) { void* p = ws + off; off = (off + bytes + 255) & ~(size_t)255; return p; };
    float*    sval    = (float*)alloc((size_t)NB * NA * 4);
    int*      cid     = (int*)alloc((size_t)NB * NA * 4);
    unsigned* hist    = (unsigned*)alloc((size_t)NB * NBIN * 4);   // 512 KB
    unsigned* cnt     = (unsigned*)alloc((size_t)NB * 64 * 4);     // adjacent: one memset covers both
    unsigned* cutbin  = (unsigned*)alloc(NB * 4);
    uint64_t* cand    = (uint64_t*)alloc((size_t)NB * CANDCAP * 8);
    float*    tval    = (float*)alloc((size_t)NB * TOPK * 4);
    float*    bx1     = (float*)alloc((size_t)NB * TOPK * 4);
    float*    by1     = (float*)alloc((size_t)NB * TOPK * 4);
    float*    bx2     = (float*)alloc((size_t)NB * TOPK * 4);
    float*    by2     = (float*)alloc((size_t)NB * TOPK * 4);
    float*    bar     = (float*)alloc((size_t)NB * TOPK * 4);
    int*      tcid    = (int*)alloc((size_t)NB * TOPK * 4);
    int*      rowflag = (int*)alloc((size_t)NB * TOPK * 4);
    uint64_t* M       = (uint64_t*)alloc((size_t)NB * TOPK * 16 * 8);

    // single memset: hist (512 KB) + cnt (4 KB, allocated contiguously after)
    hipMemsetAsync(hist, 0, (size_t)NB * NBIN * 4 + (size_t)NB * 64 * 4, stream);

    score_hist_kernel<<<NB * SBLK, 256, 0, stream>>>(x, sval, cid, hist);
    scan_kernel<<<NB, 256, 0, stream>>>(hist, cutbin);
    compact_kernel<<<NB * NA / 256, 256, 0, stream>>>(sval, cutbin, cand, cnt);
    rank_kernel<<<NB * RBLK, 256, 0, stream>>>(cand, cnt, x, cid, tval, bx1, by1, bx2, by2, bar, tcid);
    maskbuild_kernel<<<NB * 16, 256, 0, stream>>>(bx1, by1, bx2, by2, bar, tval, M, rowflag);
    sweep_kernel<<<NB, 64, 0, stream>>>(M, rowflag, tval, tcid, bx1, by1, bx2, by2, out);
}